// Round 1
// baseline (113.426 us; speedup 1.0000x reference)
//
#include <hip/hip_runtime.h>
#include <math.h>

// Problem constants (fixed-shape problem)
#define BN   2
#define CG   32      // channels per border group (128/4)
#define HH   128
#define WW   128
#define HWSZ (HH*WW) // 16384
#define KK   16384   // boxes per batch
#define TB   64      // boxes per block in main kernel

typedef float vf4 __attribute__((ext_vector_type(4)));
typedef _Float16 h8 __attribute__((ext_vector_type(8)));

// pack two f32 -> fp16 pair (RNE via v_cvt_f16_f32), a=low b=high
__device__ inline unsigned int pack_h2(float a, float b) {
  unsigned short ua = __builtin_bit_cast(unsigned short, (_Float16)a);
  unsigned short ub = __builtin_bit_cast(unsigned short, (_Float16)b);
  return (unsigned int)ua | ((unsigned int)ub << 16);
}

// ---------------------------------------------------------------------------
// Kernel 1: transpose+quantize feature [8 slabs][C=32][HW] -> ws fp16 [8][HW][C].
// All 32 channels of one spatial position become one 64B cache line.
// 1D grid with s = blk&7 so slab s is written (and stays warm) in XCD s's L2,
// matching the main kernel's per-(b,g) XCD partitioning.
// ---------------------------------------------------------------------------
__global__ __launch_bounds__(256) void transpose_f16_kernel(
    const float* __restrict__ feat, unsigned short* __restrict__ ws) {
  __shared__ uint2 lds[128 * 9];           // [i=128][8 quads + 1 pad]
  const int blk = blockIdx.x;
  const int s  = blk & 7;                  // slab 0..7 (= b*4+g) -> XCD s
  const int i0 = (blk >> 3) * 128;         // spatial tile base
  const int t  = threadIdx.x;

  const int iL = (t & 31) * 4;             // 4 consecutive positions
  const int cq = t >> 5;                   // channel quad 0..7

  const float* src = feat + (size_t)s * (CG * HWSZ) + i0 + iL;
  vf4 r[4];
#pragma unroll
  for (int cc = 0; cc < 4; ++cc)
    r[cc] = *(const vf4*)(src + (size_t)(cq * 4 + cc) * HWSZ);

#pragma unroll
  for (int ii = 0; ii < 4; ++ii) {         // register micro-transpose + pack
    uint2 q;
    q.x = pack_h2(r[0][ii], r[1][ii]);
    q.y = pack_h2(r[2][ii], r[3][ii]);
    lds[(iL + ii) * 9 + cq] = q;
  }
  __syncthreads();

  uint2* dst = (uint2*)(ws + ((size_t)s * HWSZ + i0) * CG);
  const int q2 = t & 7;
  const int ih = t >> 3;                   // 0..31
#pragma unroll
  for (int it = 0; it < 4; ++it) {
    const int i = ih + 32 * it;            // 0..127
    dst[i * 8 + q2] = lds[i * 9 + q2];     // 512B contiguous per wave
  }
}

// ---------------------------------------------------------------------------
// Kernel 2: main border-align (fp16 transposed layout), per-(b,g) blocks.
// combo s = blk&7 = b*4+g -> XCD s (round-robin dispatch), so each XCD's
// gather working set is ONE 1 MB slab, fully L2-resident and pre-warmed by
// the transpose kernel. Block = 64 boxes x 1 border x 32 ch, 256 threads;
// lane = oct (t&3, 8 channels) x box (t>>2, 0..63). Border g is
// block-uniform -> scalar shifts, no divergence.
// Output: per-g 4B NT scatter at 16B stride (25% line coverage) — traded
// against eliminating random 64B HBM refetch of the slabs.
// ---------------------------------------------------------------------------
__global__ __launch_bounds__(256) void border_align_kernel(
    const unsigned short* __restrict__ wsu, const float* __restrict__ boxes,
    const int* __restrict__ psp, float* __restrict__ out) {
  __shared__ float bxs[TB * 4];
  __shared__ float stf[64];
  __shared__ float lmax[TB * 33];          // [box][c], stride 33 (conflict-free)

  const int blk = blockIdx.x;
  const int s   = blk & 7;                 // combo -> XCD
  const int b   = s >> 2;
  const int g   = s & 3;
  const int k0  = (blk >> 3) * TB;
  const int t   = threadIdx.x;
  const int ps  = *psp;                    // pool_size (10)

  bxs[t] = boxes[((size_t)b * KK + k0) * 4 + t];          // 64 boxes * 4
  if (t < 64 && t <= ps) stf[t] = (float)t / (float)ps;   // exact f32 divide
  __syncthreads();

  const int kk  = t >> 2;                  // box 0..63 within block
  const int oct = t & 3;                   // channel oct (8 channels)
  const bool horiz = (g & 1) == 0;         // g0/g2: x moves; g1/g3: y moves
  const int mshift = horiz ? 0 : 7;        // mov coordinate * (1 or 128)
  const int fshift = horiz ? 7 : 0;        // fix coordinate * (128 or 1)

  const _Float16* slab = (const _Float16*)wsu
      + (size_t)s * (HWSZ * CG) + oct * 8;

  const float x1 = bxs[kk * 4 + 0], y1 = bxs[kk * 4 + 1];
  const float x2 = bxs[kk * 4 + 2], y2 = bxs[kk * 4 + 3];
  float mov_s, mov_d, fix;
  if (horiz) { mov_s = x1; mov_d = x2 - x1; fix = (g == 0) ? y1 : y2; }
  else       { mov_s = y1; mov_d = y2 - y1; fix = (g == 1) ? x1 : x2; }
  const bool fok = (fix > -1.0f) && (fix < 128.0f);
  const float fc = fminf(fmaxf(fix, 0.0f), 127.0f);
  const int f0 = (int)fc;
  const float lf = fc - (float)f0;
  const int f1 = min(f0 + 1, 127);
  const int bf0 = f0 << fshift;
  const int bf1 = f1 << fshift;

  h8 acc = (h8)(_Float16)(-65504.0f);      // -inf surrogate (max finite fp16)

  // per-sample address/weight computation
  float lm_c; bool ok_c; int bm0_c, bm1_c;
  auto coords = [&](int p, int& bm0, int& bm1, float& lm, bool& ok) {
    const float mov = fmaf(stf[p], mov_d, mov_s);
    ok = fok && (mov > -1.0f) && (mov < 128.0f);
    const float mc = fminf(fmaxf(mov, 0.0f), 127.0f);
    const int m0 = (int)mc;
    lm = mc - (float)m0;
    const int m1 = min(m0 + 1, 127);
    bm0 = m0 << mshift;
    bm1 = m1 << mshift;
  };

  coords(0, bm0_c, bm1_c, lm_c, ok_c);
  h8 q00 = *(const h8*)(slab + ((size_t)(bf0 + bm0_c) << 5));
  h8 q01 = *(const h8*)(slab + ((size_t)(bf0 + bm1_c) << 5));
  h8 q10 = *(const h8*)(slab + ((size_t)(bf1 + bm0_c) << 5));
  h8 q11 = *(const h8*)(slab + ((size_t)(bf1 + bm1_c) << 5));

  for (int p = 0; p <= ps; ++p) {
    const float lm = lm_c;
    const bool ok = ok_c;
    h8 f00 = q00, f01 = q01, f10 = q10, f11 = q11;
    if (p < ps) {                          // prefetch next sample's corners
      coords(p + 1, bm0_c, bm1_c, lm_c, ok_c);
      q00 = *(const h8*)(slab + ((size_t)(bf0 + bm0_c) << 5));
      q01 = *(const h8*)(slab + ((size_t)(bf0 + bm1_c) << 5));
      q10 = *(const h8*)(slab + ((size_t)(bf1 + bm0_c) << 5));
      q11 = *(const h8*)(slab + ((size_t)(bf1 + bm1_c) << 5));
    }
    const _Float16 w00 = (_Float16)((1.0f - lf) * (1.0f - lm));
    const _Float16 w01 = (_Float16)((1.0f - lf) * lm);
    const _Float16 w10 = (_Float16)(lf * (1.0f - lm));
    const _Float16 w11 = (_Float16)(lf * lm);
    h8 v = f00 * w00 + f01 * w01 + f10 * w10 + f11 * w11;  // v_pk_fma_f16
    v = ok ? v : (h8)(_Float16)0.0f;
    acc = __builtin_elementwise_max(acc, v);               // v_pk_max_f16
  }

  // Stage results as f32: lmax[box][c], stride 33.
#pragma unroll
  for (int j = 0; j < 8; ++j)
    lmax[kk * 33 + oct * 8 + j] = (float)acc[j];
  __syncthreads();

  // Per-g NT scatter: out[b][c][k0+kL][g], 64 lanes at 16B stride per wave.
  const int kL = t & 63;
  const int cb = t >> 6;                   // 0..3
  float* obase = out + ((size_t)b * CG * KK + (size_t)(k0 + kL)) * 4 + g;
#pragma unroll
  for (int it = 0; it < 8; ++it) {
    const int c = cb + 4 * it;             // 0..31
    __builtin_nontemporal_store(lmax[kL * 33 + c], obase + (size_t)c * KK * 4);
  }
}

// ---------------------------------------------------------------------------
// Fallback (ws too small): scalar gather straight from [B,4,C,H,W].
// ---------------------------------------------------------------------------
__global__ __launch_bounds__(128) void border_align_fallback(
    const float* __restrict__ base, const float* __restrict__ boxes,
    const int* __restrict__ psp, float* __restrict__ out) {
  const int blk = blockIdx.x;
  const int b = blk >> 10;
  const int t = threadIdx.x;
  const int g = t >> 5, c = t & 31;
  const int k0 = (blk & 1023) * 16;
  const int ps = *psp;
  const float psf = (float)ps;
  const float* slab = base + (size_t)(b * 4 + g) * (CG * HWSZ) + (size_t)c * HWSZ;
  for (int kk = 0; kk < 16; ++kk) {
    const int kbox = k0 + kk;
    const float x1 = boxes[((size_t)b * KK + kbox) * 4 + 0];
    const float y1 = boxes[((size_t)b * KK + kbox) * 4 + 1];
    const float x2 = boxes[((size_t)b * KK + kbox) * 4 + 2];
    const float y2 = boxes[((size_t)b * KK + kbox) * 4 + 3];
    float m = -INFINITY;
    for (int p = 0; p <= ps; ++p) {
      const float tf = (float)p / psf;
      float x, y;
      if      (g == 0) { x = x1 + tf * (x2 - x1); y = y1; }
      else if (g == 1) { x = x1; y = y1 + tf * (y2 - y1); }
      else if (g == 2) { x = x1 + tf * (x2 - x1); y = y2; }
      else             { x = x2; y = y1 + tf * (y2 - y1); }
      const bool valid = (x > -1.0f) && (x < 128.0f) && (y > -1.0f) && (y < 128.0f);
      const float xc = fminf(fmaxf(x, 0.0f), 127.0f);
      const float yc = fminf(fmaxf(y, 0.0f), 127.0f);
      const int x0 = (int)xc, y0 = (int)yc;
      const float lx = xc - (float)x0, ly = yc - (float)y0;
      const int x1i = min(x0 + 1, 127), y1i = min(y0 + 1, 127);
      const float f00 = slab[y0 * WW + x0],  f01 = slab[y0 * WW + x1i];
      const float f10 = slab[y1i * WW + x0], f11 = slab[y1i * WW + x1i];
      float v = f00 * (1 - ly) * (1 - lx) + f01 * (1 - ly) * lx
              + f10 * ly * (1 - lx) + f11 * ly * lx;
      v = valid ? v : 0.0f;
      m = fmaxf(m, v);
    }
    out[(((size_t)(b * CG + c)) * KK + kbox) * 4 + g] = m;
  }
}

extern "C" void kernel_launch(void* const* d_in, const int* in_sizes, int n_in,
                              void* d_out, int out_size, void* d_ws, size_t ws_size,
                              hipStream_t stream) {
  const float* feature = (const float*)d_in[0];
  const float* boxes   = (const float*)d_in[1];
  const int*   psp     = (const int*)d_in[2];
  float*       out     = (float*)d_out;

  const size_t need = (size_t)BN * 4 * CG * HWSZ * sizeof(unsigned short); // 8 MiB
  if (ws_size >= need) {
    unsigned short* ws = (unsigned short*)d_ws;
    hipLaunchKernelGGL(transpose_f16_kernel, dim3(8 * (HWSZ / 128)),
                       dim3(256), 0, stream, feature, ws);
    hipLaunchKernelGGL(border_align_kernel, dim3(BN * 4 * (KK / TB)), dim3(256),
                       0, stream, ws, boxes, psp, out);
  } else {
    hipLaunchKernelGGL(border_align_fallback, dim3(BN * (KK / 16)), dim3(128), 0,
                       stream, feature, boxes, psp, out);
  }
}

// Round 2
// 95.868 us; speedup vs baseline: 1.1831x; 1.1831x over previous
//
#include <hip/hip_runtime.h>
#include <math.h>

// Problem constants (fixed-shape problem)
#define BN   2
#define CG   32      // channels per border group (128/4)
#define HH   128
#define WW   128
#define HWSZ (HH*WW) // 16384
#define KK   16384   // boxes per batch
#define TK   16      // boxes per block in main kernel

typedef float vf4 __attribute__((ext_vector_type(4)));
typedef _Float16 h8 __attribute__((ext_vector_type(8)));

// pack two f32 -> fp16 pair (RNE via v_cvt_f16_f32), a=low b=high
__device__ inline unsigned int pack_h2(float a, float b) {
  unsigned short ua = __builtin_bit_cast(unsigned short, (_Float16)a);
  unsigned short ub = __builtin_bit_cast(unsigned short, (_Float16)b);
  return (unsigned int)ua | ((unsigned int)ub << 16);
}

// ---------------------------------------------------------------------------
// Kernel 1: transpose+quantize feature [8 slabs][C=32][HW] -> ws fp16 [8][HW][C].
// All 32 channels of one spatial position become one 64B cache line.
// ---------------------------------------------------------------------------
__global__ __launch_bounds__(256) void transpose_f16_kernel(
    const float* __restrict__ feat, unsigned short* __restrict__ ws) {
  __shared__ uint2 lds[128 * 9];           // [i=128][8 quads + 1 pad]
  const int s  = blockIdx.y;               // slab 0..7 (= b*4+g)
  const int i0 = blockIdx.x * 128;         // spatial tile base
  const int t  = threadIdx.x;

  const int iL = (t & 31) * 4;             // 4 consecutive positions
  const int cq = t >> 5;                   // channel quad 0..7

  const float* src = feat + (size_t)s * (CG * HWSZ) + i0 + iL;
  vf4 r[4];
#pragma unroll
  for (int cc = 0; cc < 4; ++cc)
    r[cc] = *(const vf4*)(src + (size_t)(cq * 4 + cc) * HWSZ);

#pragma unroll
  for (int ii = 0; ii < 4; ++ii) {         // register micro-transpose + pack
    uint2 q;
    q.x = pack_h2(r[0][ii], r[1][ii]);
    q.y = pack_h2(r[2][ii], r[3][ii]);
    lds[(iL + ii) * 9 + cq] = q;
  }
  __syncthreads();

  uint2* dst = (uint2*)(ws + ((size_t)s * HWSZ + i0) * CG);
  const int q2 = t & 7;
  const int ih = t >> 3;                   // 0..31
#pragma unroll
  for (int it = 0; it < 4; ++it) {
    const int i = ih + 32 * it;            // 0..127
    dst[i * 8 + q2] = lds[i * 9 + q2];     // 512B contiguous per wave
  }
}

// ---------------------------------------------------------------------------
// Kernel 2: main border-align (fp16 transposed layout).
// Block = 16 boxes, 256 threads = 4 waves; wave w handles border g=w
// (wave-uniform -> scalar control). Lane = oct (t&3, 8 channels) x
// kk (lane>>2, box 0..15). Per corner: 4 lanes x 16B = one 64B line.
//
// b = blk&1: under blk%8 XCD round-robin, batch 0 lives on even XCDs,
// batch 1 on odd -> per-XCD gather working set = 4 MB (its L2 size).
//
// DEPTH-3 SOFTWARE PIPELINE: 3 samples' corner loads (12 loads) in flight
// per thread; the consume of sample p overlaps the latency of p+1,p+2 and
// the refill of p+3. The counters showed the kernel latency-bound (VALU 23%,
// HBM 1%, LDS 0) -- this attacks the serial 11-iteration gather chain.
// ---------------------------------------------------------------------------
__global__ __launch_bounds__(256) void border_align_kernel(
    const unsigned short* __restrict__ wsu, const float* __restrict__ boxes,
    const int* __restrict__ psp, float* __restrict__ out) {
  __shared__ float bxs[TK * 4];
  __shared__ float stf[64];
  __shared__ float lmax[TK * 4 * 33];      // [kg=k*4+g][c], stride 33

  const int blk = blockIdx.x;
  const int b   = blk & 1;                 // batch -> XCD parity
  const int k0  = (blk >> 1) * TK;
  const int t   = threadIdx.x;
  const int ps  = *psp;                    // pool_size (10)

  if (t < TK * 4) bxs[t] = boxes[((size_t)b * KK + k0) * 4 + t];
  if (t < 64) stf[t] = (float)(t <= ps ? t : ps) / (float)ps;
  __syncthreads();

  const int g   = t >> 6;                  // border 0..3 (wave-uniform)
  const int oct = t & 3;                   // channel oct (8 channels)
  const int kk  = (t >> 2) & 15;           // box 0..15
  const bool horiz = (g & 1) == 0;         // g0/g2: x moves; g1/g3: y moves
  const int mshift = horiz ? 0 : 7;        // mov coordinate * (1 or 128)
  const int fshift = horiz ? 7 : 0;        // fix coordinate * (128 or 1)

  const _Float16* slab = (const _Float16*)wsu
      + (size_t)(b * 4 + g) * (HWSZ * CG) + oct * 8;

  const float x1 = bxs[kk * 4 + 0], y1 = bxs[kk * 4 + 1];
  const float x2 = bxs[kk * 4 + 2], y2 = bxs[kk * 4 + 3];
  float mov_s, mov_d, fix;
  if (horiz) { mov_s = x1; mov_d = x2 - x1; fix = (g == 0) ? y1 : y2; }
  else       { mov_s = y1; mov_d = y2 - y1; fix = (g == 1) ? x1 : x2; }
  const bool fok = (fix > -1.0f) && (fix < 128.0f);
  const float fc = fminf(fmaxf(fix, 0.0f), 127.0f);
  const int f0 = (int)fc;
  const float lf = fc - (float)f0;
  const int f1 = min(f0 + 1, 127);
  const int bf0 = f0 << fshift;
  const int bf1 = f1 << fshift;

  h8 acc = (h8)(_Float16)(-65504.0f);      // -inf surrogate (max finite fp16)

// issue sample P's 4 corner gathers into slot (Q0..Q3, LM, OK)
#define ISSUE(P, Q0, Q1, Q2, Q3, LM, OK) do {                              \
    const float mov_ = fmaf(stf[(P)], mov_d, mov_s);                       \
    OK = fok && (mov_ > -1.0f) && (mov_ < 128.0f);                         \
    const float mc_ = fminf(fmaxf(mov_, 0.0f), 127.0f);                    \
    const int m0_ = (int)mc_;                                              \
    LM = mc_ - (float)m0_;                                                 \
    const int m1_ = min(m0_ + 1, 127);                                     \
    const int bm0_ = m0_ << mshift, bm1_ = m1_ << mshift;                  \
    Q0 = *(const h8*)(slab + ((size_t)(bf0 + bm0_) << 5));                 \
    Q1 = *(const h8*)(slab + ((size_t)(bf0 + bm1_) << 5));                 \
    Q2 = *(const h8*)(slab + ((size_t)(bf1 + bm0_) << 5));                 \
    Q3 = *(const h8*)(slab + ((size_t)(bf1 + bm1_) << 5));                 \
  } while (0)

// bilinear + mask + running max on one sample's corners
#define CONSUME(Q0, Q1, Q2, Q3, LM, OK) do {                               \
    const float lm_ = LM;                                                  \
    const _Float16 w00 = (_Float16)((1.0f - lf) * (1.0f - lm_));           \
    const _Float16 w01 = (_Float16)((1.0f - lf) * lm_);                    \
    const _Float16 w10 = (_Float16)(lf * (1.0f - lm_));                    \
    const _Float16 w11 = (_Float16)(lf * lm_);                             \
    h8 v_ = Q0 * w00 + Q1 * w01 + Q2 * w10 + Q3 * w11;                     \
    v_ = (OK) ? v_ : (h8)(_Float16)0.0f;                                   \
    acc = __builtin_elementwise_max(acc, v_);                              \
  } while (0)

  h8 qA0, qA1, qA2, qA3, qB0, qB1, qB2, qB3, qC0, qC1, qC2, qC3;
  float lmA, lmB, lmC;
  bool okA, okB, okC;

  // prologue: fill 3 slots (samples 0,1,2). stf[] is defined for idx<64 and
  // clamps to ps, so over-range prologue indices produce safe in-bounds
  // addresses whose values are never consumed.
  ISSUE(0, qA0, qA1, qA2, qA3, lmA, okA);
  ISSUE(1, qB0, qB1, qB2, qB3, lmB, okB);
  ISSUE(2, qC0, qC1, qC2, qC3, lmC, okC);

  int p = 0;
  for (; p + 2 <= ps; p += 3) {
    {
      h8 f0 = qA0, f1 = qA1, f2 = qA2, f3 = qA3;
      const float lm = lmA; const bool ok = okA;
      if (p + 3 <= ps) ISSUE(p + 3, qA0, qA1, qA2, qA3, lmA, okA);
      CONSUME(f0, f1, f2, f3, lm, ok);
    }
    {
      h8 f0 = qB0, f1 = qB1, f2 = qB2, f3 = qB3;
      const float lm = lmB; const bool ok = okB;
      if (p + 4 <= ps) ISSUE(p + 4, qB0, qB1, qB2, qB3, lmB, okB);
      CONSUME(f0, f1, f2, f3, lm, ok);
    }
    {
      h8 f0 = qC0, f1 = qC1, f2 = qC2, f3 = qC3;
      const float lm = lmC; const bool ok = okC;
      if (p + 5 <= ps) ISSUE(p + 5, qC0, qC1, qC2, qC3, lmC, okC);
      CONSUME(f0, f1, f2, f3, lm, ok);
    }
  }
  if (p <= ps)     CONSUME(qA0, qA1, qA2, qA3, lmA, okA);
  if (p + 1 <= ps) CONSUME(qB0, qB1, qB2, qB3, lmB, okB);

#undef ISSUE
#undef CONSUME

  // Stage results as f32: lmax[kg][c], stride 33.
  const int kg = kk * 4 + g;
#pragma unroll
  for (int j = 0; j < 8; ++j)
    lmax[kg * 33 + oct * 8 + j] = (float)acc[j];
  __syncthreads();

  // Coalesced nontemporal write: out[b][c][k0..k0+15][g]: 256B run per c.
  const int kgq = t & 15;                  // float4 index along kg (0..15)
  const int cb  = t >> 4;                  // 0..15
#pragma unroll
  for (int it = 0; it < 2; ++it) {
    const int c = cb + 16 * it;            // 0..31
    vf4 v;
#pragma unroll
    for (int j = 0; j < 4; ++j)
      v[j] = lmax[(kgq * 4 + j) * 33 + c];
    vf4* dst = (vf4*)(out + ((size_t)(b * CG + c) * KK + k0) * 4 + kgq * 4);
    __builtin_nontemporal_store(v, dst);
  }
}

// ---------------------------------------------------------------------------
// Fallback (ws too small): scalar gather straight from [B,4,C,H,W].
// ---------------------------------------------------------------------------
__global__ __launch_bounds__(128) void border_align_fallback(
    const float* __restrict__ base, const float* __restrict__ boxes,
    const int* __restrict__ psp, float* __restrict__ out) {
  const int blk = blockIdx.x;
  const int b = blk >> 10;
  const int t = threadIdx.x;
  const int g = t >> 5, c = t & 31;
  const int k0 = (blk & 1023) * 16;
  const int ps = *psp;
  const float psf = (float)ps;
  const float* slab = base + (size_t)(b * 4 + g) * (CG * HWSZ) + (size_t)c * HWSZ;
  for (int kk = 0; kk < 16; ++kk) {
    const int kbox = k0 + kk;
    const float x1 = boxes[((size_t)b * KK + kbox) * 4 + 0];
    const float y1 = boxes[((size_t)b * KK + kbox) * 4 + 1];
    const float x2 = boxes[((size_t)b * KK + kbox) * 4 + 2];
    const float y2 = boxes[((size_t)b * KK + kbox) * 4 + 3];
    float m = -INFINITY;
    for (int p = 0; p <= ps; ++p) {
      const float tf = (float)p / psf;
      float x, y;
      if      (g == 0) { x = x1 + tf * (x2 - x1); y = y1; }
      else if (g == 1) { x = x1; y = y1 + tf * (y2 - y1); }
      else if (g == 2) { x = x1 + tf * (x2 - x1); y = y2; }
      else             { x = x2; y = y1 + tf * (y2 - y1); }
      const bool valid = (x > -1.0f) && (x < 128.0f) && (y > -1.0f) && (y < 128.0f);
      const float xc = fminf(fmaxf(x, 0.0f), 127.0f);
      const float yc = fminf(fmaxf(y, 0.0f), 127.0f);
      const int x0 = (int)xc, y0 = (int)yc;
      const float lx = xc - (float)x0, ly = yc - (float)y0;
      const int x1i = min(x0 + 1, 127), y1i = min(y0 + 1, 127);
      const float f00 = slab[y0 * WW + x0],  f01 = slab[y0 * WW + x1i];
      const float f10 = slab[y1i * WW + x0], f11 = slab[y1i * WW + x1i];
      float v = f00 * (1 - ly) * (1 - lx) + f01 * (1 - ly) * lx
              + f10 * ly * (1 - lx) + f11 * ly * lx;
      v = valid ? v : 0.0f;
      m = fmaxf(m, v);
    }
    out[(((size_t)(b * CG + c)) * KK + kbox) * 4 + g] = m;
  }
}

extern "C" void kernel_launch(void* const* d_in, const int* in_sizes, int n_in,
                              void* d_out, int out_size, void* d_ws, size_t ws_size,
                              hipStream_t stream) {
  const float* feature = (const float*)d_in[0];
  const float* boxes   = (const float*)d_in[1];
  const int*   psp     = (const int*)d_in[2];
  float*       out     = (float*)d_out;

  const size_t need = (size_t)BN * 4 * CG * HWSZ * sizeof(unsigned short); // 8 MiB
  if (ws_size >= need) {
    unsigned short* ws = (unsigned short*)d_ws;
    hipLaunchKernelGGL(transpose_f16_kernel, dim3(HWSZ / 128, BN * 4),
                       dim3(256), 0, stream, feature, ws);
    hipLaunchKernelGGL(border_align_kernel, dim3(BN * (KK / TK)), dim3(256), 0,
                       stream, ws, boxes, psp, out);
  } else {
    hipLaunchKernelGGL(border_align_fallback, dim3(BN * (KK / 16)), dim3(128), 0,
                       stream, feature, boxes, psp, out);
  }
}